// Round 1
// baseline (4115.424 us; speedup 1.0000x reference)
//
#include <hip/hip_runtime.h>
#include <stdint.h>

#define BATCH 2048
#define TSEQ  64
#define DIN   512
#define HID   1024
#define CIN   1536   // DIN + HID

#define BM 128
#define BN 32
#define BK 64
#define KITERS (CIN / BK)   // 24
#define NBLOCKS 512

// LDS geometry: 8-row chunks of 128 B rows (1024 B data) + 64 B pad -> stride 1088 B.
// (r>>3) chunk step lands +16 banks; row-within-chunk +0; lane quads +4; 8/8 lane split
// covers +0/+16 -> b128 fragment reads hit all 32 banks exactly 8x (conflict-free).
#define CHUNK   1088
#define A_CHUNKS 16                     // 128 rows
#define B_CHUNKS 4                      // 32 rows per matrix
#define A_BYTES (A_CHUNKS * CHUNK)      // 17408
#define B_MAT   (B_CHUNKS * CHUNK)      // 4352
#define BUF_BYTES (A_BYTES + 3 * B_MAT) // 30464  (dbuf 60928 -> exactly 2 blocks/CU)

typedef __attribute__((ext_vector_type(8))) short bf16x8;
typedef __attribute__((ext_vector_type(4))) float f32x4;
typedef __attribute__((ext_vector_type(4))) float fvec4;
typedef __attribute__((ext_vector_type(4))) unsigned int uvec4;

// RNE float -> bf16 (bits)
__device__ __forceinline__ unsigned short f2bf(float f) {
    unsigned int u = __float_as_uint(f);
    u += 0x7fffu + ((u >> 16) & 1u);
    return (unsigned short)(u >> 16);
}
__device__ __forceinline__ float bf2f(unsigned short u) {
    return __uint_as_float(((unsigned int)u) << 16);
}

// async global->LDS, 16B per lane; lane i lands at ldsbase + i*16 (wave-uniform base).
__device__ __forceinline__ void gload_lds16(const void* g, void* lds) {
    __builtin_amdgcn_global_load_lds(
        (const __attribute__((address_space(1))) void*)(uintptr_t)g,
        (__attribute__((address_space(3))) void*)(unsigned)(uintptr_t)lds,
        16, 0, 0);
}

// ---------------- weight conversion: fp32 -> bf16, 3 matrices [HID][CIN] ----------------
__global__ __launch_bounds__(256) void convert_w(const float* __restrict__ Wf,
                                                 const float* __restrict__ Wg,
                                                 const float* __restrict__ Wh,
                                                 unsigned short* __restrict__ Wb) {
    int mat = blockIdx.y;
    const float* src = (mat == 0) ? Wf : ((mat == 1) ? Wg : Wh);
    size_t base = (size_t)mat * (size_t)(HID * CIN);
    size_t idx = ((size_t)blockIdx.x * 256 + threadIdx.x) * 8;
    const fvec4* s = (const fvec4*)(src + idx);
    fvec4 a = s[0], b = s[1];
    uvec4 o;
    o.x = (unsigned)f2bf(a.x) | ((unsigned)f2bf(a.y) << 16);
    o.y = (unsigned)f2bf(a.z) | ((unsigned)f2bf(a.w) << 16);
    o.z = (unsigned)f2bf(b.x) | ((unsigned)f2bf(b.y) << 16);
    o.w = (unsigned)f2bf(b.z) | ((unsigned)f2bf(b.w) << 16);
    *(uvec4*)(Wb + base + idx) = o;
}

// ---------------- x conversion: [B][T][D] fp32 -> [T][B][D] bf16 (time-major) ----------------
__global__ __launch_bounds__(256) void convert_x(const float* __restrict__ x,
                                                 unsigned short* __restrict__ xb) {
    size_t e = ((size_t)blockIdx.x * 256 + threadIdx.x) * 8;
    int t   = (int)(e / ((size_t)BATCH * DIN));
    int rem = (int)(e % ((size_t)BATCH * DIN));
    int b = rem / DIN;
    int d = rem % DIN;
    const float* src = x + ((size_t)b * TSEQ + t) * DIN + d;
    fvec4 a = *(const fvec4*)src;
    fvec4 c = *(const fvec4*)(src + 4);
    uvec4 o;
    o.x = (unsigned)f2bf(a.x) | ((unsigned)f2bf(a.y) << 16);
    o.y = (unsigned)f2bf(a.z) | ((unsigned)f2bf(a.w) << 16);
    o.z = (unsigned)f2bf(c.x) | ((unsigned)f2bf(c.y) << 16);
    o.w = (unsigned)f2bf(c.z) | ((unsigned)f2bf(c.w) << 16);
    *(uvec4*)(xb + e) = o;
}

// ---------------- persistent kernel: all 64 recurrence steps in one dispatch ----------------
// Co-residency is guaranteed structurally: static LDS 60928 B caps occupancy at
// floor(163840/60928) = 2 blocks/CU; grid = 512 = 2 x 256 CUs; VGPR well under the
// 256/wave bound enforced by __launch_bounds__(256,2). All blocks are resident before
// any barrier wait, so the device-scope grid barrier cannot deadlock.
// Cross-XCD h visibility: release = per-wave vmcnt(0) at __syncthreads + thread0
// __threadfence (agent-scope L2 writeback) before arrive; acquire = __threadfence
// (L2/L1 invalidate) after spin, then __syncthreads. x/W are read-only (no hazard).
__global__ __launch_bounds__(256, 2) void lnn_steps(
    const unsigned short* __restrict__ xb,     // bf16 [TSEQ][BATCH][DIN]
    const unsigned short* __restrict__ Wb,     // bf16 [3][HID][CIN]
    const float* __restrict__ bfv,
    const float* __restrict__ bgv,
    const float* __restrict__ bhv,
    unsigned short* __restrict__ hA,           // bf16 [BATCH][HID]  (h_0 = 0, final h)
    unsigned short* __restrict__ hB,           // bf16 [BATCH][HID]
    unsigned* bar)                             // zeroed per launch; 8 sub-counters + master
{
    __shared__ __align__(16) char lds[2][BUF_BYTES];   // 60928 B

    const int tid  = threadIdx.x;
    const int bid  = blockIdx.x;
    // n-affinity XCD swizzle: XCD (bid&7) sees n_tiles {4k..4k+3} -> 1.18 MB weight slice in L2
    const int n_tile = ((bid & 7) << 2) | ((bid >> 3) & 3);   // 0..31
    const int m_tile = bid >> 5;                              // 0..15
    const int m0 = m_tile * BM;
    const int n0 = n_tile * BN;

    const int lane = tid & 63;
    const int wave = tid >> 6;       // 0..3
    const int wm = wave >> 1;        // 0..1 : 64-row half
    const int wn = wave & 1;         // 0..1 : 16-col half

    // DMA lane mapping inside an 8-row x 128 B chunk
    const int drow = lane >> 3;          // 0..7
    const int dcol = (lane & 7) * 8;     // elem col 0..56

    const int cg = n0 + wn * 16 + (lane & 15);
    const float biasF = bfv[cg];
    const float biasG = bgv[cg];
    const float biasH = bhv[cg];

    // precomputed fragment read offsets (bytes) — loop-invariant across all 64 steps now
    int aoff[4];
#pragma unroll
    for (int mt = 0; mt < 4; ++mt) {
        int r = wm * 64 + mt * 16 + (lane & 15);
        aoff[mt] = (r >> 3) * CHUNK + (r & 7) * 128;
    }
    const int nloc = wn * 16 + (lane & 15);
    const int boff = (nloc >> 3) * CHUNK + (nloc & 7) * 128;
    const int kboff = (lane >> 4) * 16;   // this lane's 8-elem K-slice within a 128-B row

    auto stage = [&](int ki, char* base, const unsigned short* xsrc, const unsigned short* hin) {
        const int k0 = ki * BK;
        const unsigned short* asrc;
        int astride;
        if (k0 < DIN) { asrc = xsrc + k0;        astride = DIN; }
        else          { asrc = hin + (k0 - DIN); astride = HID; }
        // A: wave w stages chunks 4w..4w+3 (rows 32w..32w+31)
#pragma unroll
        for (int c = 0; c < 4; ++c) {
            int chunk = wave * 4 + c;
            gload_lds16(asrc + (size_t)(m0 + chunk * 8 + drow) * astride + dcol,
                        base + chunk * CHUNK);
        }
        // B: 12 chunk-units (mat = u>>2, chunk = u&3); wave w stages u = 3w..3w+2
#pragma unroll
        for (int j = 0; j < 3; ++j) {
            int u = wave * 3 + j;
            int mat = u >> 2, chunk = u & 3;
            gload_lds16(Wb + (size_t)mat * (HID * CIN) + (size_t)(n0 + chunk * 8 + drow) * CIN
                           + k0 + dcol,
                        base + A_BYTES + mat * B_MAT + chunk * CHUNK);
        }
    };

    // prologue: first k-tile of t=0 is x-only (k0=0 < DIN); hA arg unused in that branch
    stage(0, lds[0], xb, hA);

    for (int t = 0; t < TSEQ; ++t) {
        const unsigned short* xsrc = xb + (size_t)t * BATCH * DIN;
        const unsigned short* hin  = (t & 1) ? hB : hA;
        unsigned short*       hout = (t & 1) ? hA : hB;

        f32x4 acc[3][4] = {};

        for (int ki = 0; ki < KITERS; ++ki) {
            const int bb = ki & 1;
            __syncthreads();                              // drains DMA(ki); prior readers done
            if (ki < KITERS - 1) stage(ki + 1, lds[bb ^ 1], xsrc, hin);
            const char* base = lds[bb];
#pragma unroll
            for (int ks = 0; ks < 2; ++ks) {
                const int kb = ks * 64 + kboff;
                bf16x8 af[4];
#pragma unroll
                for (int mt = 0; mt < 4; ++mt)
                    af[mt] = *(const bf16x8*)(base + aoff[mt] + kb);
#pragma unroll
                for (int mat = 0; mat < 3; ++mat) {
                    bf16x8 bq = *(const bf16x8*)(base + A_BYTES + mat * B_MAT + boff + kb);
#pragma unroll
                    for (int mt = 0; mt < 4; ++mt)
                        acc[mat][mt] = __builtin_amdgcn_mfma_f32_16x16x32_bf16(
                            af[mt], bq, acc[mat][mt], 0, 0, 0);
                }
            }
        }

        // epilogue: gate + NT store bf16 h_out
        // C/D layout (16x16x32): col = lane&15, row = (lane>>4)*4 + reg   [m89-verified]
#pragma unroll
        for (int mt = 0; mt < 4; ++mt) {
            int rbase = m0 + wm * 64 + mt * 16 + (lane >> 4) * 4;
#pragma unroll
            for (int r = 0; r < 4; ++r) {
                float f  = acc[0][mt][r] + biasF;
                float g  = acc[1][mt][r] + biasG;
                float hh = acc[2][mt][r] + biasH;
                float gate = 1.0f / (1.0f + __expf(f));   // sigmoid(-f)
                float nh = hh + gate * (g - hh);
                __builtin_nontemporal_store(f2bf(nh),
                    hout + (size_t)(rbase + r) * HID + cg);
            }
        }

        if (t + 1 < TSEQ) {
            __syncthreads();   // every wave: LDS reads done + its h stores vmcnt(0)-drained
            // prefetch next step's first k-tile (x-only, independent of h_{t+1}) so the
            // DMA flies during the grid-barrier spin; lds[0] is free (last read at ki=22)
            stage(0, lds[0], xsrc + (size_t)BATCH * DIN, hin);
            if (tid == 0) {
                __threadfence();                           // release: agent-scope L2 writeback
                // 8-way-split arrive counters (128 B apart) to avoid 512-way same-line RMW;
                // last arriver of each sub bumps the master; everyone spins on master.
                unsigned* sub    = bar + ((bid & 7) << 5);
                unsigned* master = bar + 256;
                unsigned a = __hip_atomic_fetch_add(sub, 1u, __ATOMIC_ACQ_REL,
                                                    __HIP_MEMORY_SCOPE_AGENT);
                if (a == (unsigned)(t + 1) * (NBLOCKS / 8) - 1u)
                    __hip_atomic_fetch_add(master, 1u, __ATOMIC_ACQ_REL,
                                           __HIP_MEMORY_SCOPE_AGENT);
                const unsigned mtarget = (unsigned)(t + 1) * 8u;
                while (__hip_atomic_load(master, __ATOMIC_RELAXED,
                                         __HIP_MEMORY_SCOPE_AGENT) < mtarget)
                    __builtin_amdgcn_s_sleep(2);
                __threadfence();                           // acquire: invalidate stale L1/L2
            }
            __syncthreads();
        }
    }
}

// ---------------- final FC: out[2048][2] = h @ Wfc^T + bfc ----------------
__global__ __launch_bounds__(256) void fc_kernel(const unsigned short* __restrict__ h,
                                                 const float* __restrict__ Wfc,
                                                 const float* __restrict__ bfc,
                                                 float* __restrict__ out) {
    int row = blockIdx.x;
    int tid = threadIdx.x;
    const unsigned short* hr = h + (size_t)row * HID;
    ushort4 hv = *(const ushort4*)(hr + tid * 4);
    float h0 = bf2f(hv.x), h1 = bf2f(hv.y), h2 = bf2f(hv.z), h3 = bf2f(hv.w);
    float4 w0 = *(const float4*)(Wfc + tid * 4);
    float4 w1 = *(const float4*)(Wfc + HID + tid * 4);
    float a0 = h0 * w0.x + h1 * w0.y + h2 * w0.z + h3 * w0.w;
    float a1 = h0 * w1.x + h1 * w1.y + h2 * w1.z + h3 * w1.w;
#pragma unroll
    for (int off = 32; off > 0; off >>= 1) {
        a0 += __shfl_down(a0, off);
        a1 += __shfl_down(a1, off);
    }
    __shared__ float red[2][4];
    if ((tid & 63) == 0) { red[0][tid >> 6] = a0; red[1][tid >> 6] = a1; }
    __syncthreads();
    if (tid == 0) out[(size_t)row * 2 + 0] = red[0][0] + red[0][1] + red[0][2] + red[0][3] + bfc[0];
    if (tid == 1) out[(size_t)row * 2 + 1] = red[1][0] + red[1][1] + red[1][2] + red[1][3] + bfc[1];
}

extern "C" void kernel_launch(void* const* d_in, const int* in_sizes, int n_in,
                              void* d_out, int out_size, void* d_ws, size_t ws_size,
                              hipStream_t stream) {
    const float* x   = (const float*)d_in[0];
    const float* Wf  = (const float*)d_in[1];
    const float* bfv = (const float*)d_in[2];
    const float* Wg  = (const float*)d_in[3];
    const float* bgv = (const float*)d_in[4];
    const float* Wh  = (const float*)d_in[5];
    const float* bhv = (const float*)d_in[6];
    const float* Wfc = (const float*)d_in[7];
    const float* bfc = (const float*)d_in[8];
    float* out = (float*)d_out;

    char* ws = (char*)d_ws;
    unsigned short* Wb = (unsigned short*)ws;                       // 9.4 MB
    size_t wb_bytes = (size_t)3 * HID * CIN * 2;
    size_t h_bytes  = (size_t)BATCH * HID * 2;                      // 4 MB
    size_t xb_bytes = (size_t)TSEQ * BATCH * DIN * 2;               // 128 MB
    unsigned short* h0 = (unsigned short*)(ws + wb_bytes);
    unsigned short* h1 = (unsigned short*)(ws + wb_bytes + h_bytes);
    unsigned short* xbuf = (unsigned short*)(ws + wb_bytes + 2 * h_bytes);
    unsigned* bar = (unsigned*)(ws + wb_bytes + 2 * h_bytes + xb_bytes);
    // total ws use ~146 MB (harness ws ~1 GiB)

    convert_w<<<dim3(768, 3), 256, 0, stream>>>(Wf, Wg, Wh, Wb);
    convert_x<<<32768, 256, 0, stream>>>(x, xbuf);
    (void)hipMemsetAsync(h0, 0, h_bytes, stream);                   // h_0 = 0 (capturable)
    (void)hipMemsetAsync(bar, 0, 2048, stream);                     // barrier counters per launch

    lnn_steps<<<NBLOCKS, 256, 0, stream>>>(xbuf, Wb, bfv, bgv, bhv, h0, h1, bar);
    // after 64 steps (even count), final h is in h0
    fc_kernel<<<BATCH, 256, 0, stream>>>(h0, Wfc, bfc, out);
}

// Round 2
// 3060.473 us; speedup vs baseline: 1.3447x; 1.3447x over previous
//
#include <hip/hip_runtime.h>
#include <stdint.h>

#define BATCH 2048
#define TSEQ  64
#define DIN   512
#define HID   1024
#define CIN   1536   // DIN + HID

#define BM 128
#define BN 32
#define BK 64
#define KITERS (CIN / BK)   // 24

// LDS geometry (A tile only now): 8-row chunks of 128 B rows (1024 B data) + 64 B pad
// -> stride 1088 B. (r>>3) chunk step lands +16 banks; lane quads +4; 8/8 lane split
// covers +0/+16 -> b128 fragment reads hit all 32 banks exactly 8x (balanced/minimal).
#define CHUNK   1088
#define A_CHUNKS 16                     // 128 rows
#define A_BYTES (A_CHUNKS * CHUNK)      // 17408; dbuf 34816 -> LDS no longer caps occupancy

typedef __attribute__((ext_vector_type(8))) short bf16x8;
typedef __attribute__((ext_vector_type(4))) float f32x4;
typedef __attribute__((ext_vector_type(4))) float fvec4;
typedef __attribute__((ext_vector_type(4))) unsigned int uvec4;

// RNE float -> bf16 (bits)
__device__ __forceinline__ unsigned short f2bf(float f) {
    unsigned int u = __float_as_uint(f);
    u += 0x7fffu + ((u >> 16) & 1u);
    return (unsigned short)(u >> 16);
}
__device__ __forceinline__ float bf2f(unsigned short u) {
    return __uint_as_float(((unsigned int)u) << 16);
}

// async global->LDS, 16B per lane; lane i lands at ldsbase + i*16 (wave-uniform base).
__device__ __forceinline__ void gload_lds16(const void* g, void* lds) {
    __builtin_amdgcn_global_load_lds(
        (const __attribute__((address_space(1))) void*)(uintptr_t)g,
        (__attribute__((address_space(3))) void*)(unsigned)(uintptr_t)lds,
        16, 0, 0);
}

// ---------------- weight conversion: fp32 -> bf16, 3 matrices [HID][CIN] ----------------
__global__ __launch_bounds__(256) void convert_w(const float* __restrict__ Wf,
                                                 const float* __restrict__ Wg,
                                                 const float* __restrict__ Wh,
                                                 unsigned short* __restrict__ Wb) {
    int mat = blockIdx.y;
    const float* src = (mat == 0) ? Wf : ((mat == 1) ? Wg : Wh);
    size_t base = (size_t)mat * (size_t)(HID * CIN);
    size_t idx = ((size_t)blockIdx.x * 256 + threadIdx.x) * 8;
    const fvec4* s = (const fvec4*)(src + idx);
    fvec4 a = s[0], b = s[1];
    uvec4 o;
    o.x = (unsigned)f2bf(a.x) | ((unsigned)f2bf(a.y) << 16);
    o.y = (unsigned)f2bf(a.z) | ((unsigned)f2bf(a.w) << 16);
    o.z = (unsigned)f2bf(b.x) | ((unsigned)f2bf(b.y) << 16);
    o.w = (unsigned)f2bf(b.z) | ((unsigned)f2bf(b.w) << 16);
    *(uvec4*)(Wb + base + idx) = o;
}

// ---------------- x conversion: [B][T][D] fp32 -> [T][B][D] bf16 (time-major) ----------------
__global__ __launch_bounds__(256) void convert_x(const float* __restrict__ x,
                                                 unsigned short* __restrict__ xb) {
    size_t e = ((size_t)blockIdx.x * 256 + threadIdx.x) * 8;
    int t   = (int)(e / ((size_t)BATCH * DIN));
    int rem = (int)(e % ((size_t)BATCH * DIN));
    int b = rem / DIN;
    int d = rem % DIN;
    const float* src = x + ((size_t)b * TSEQ + t) * DIN + d;
    fvec4 a = *(const fvec4*)src;
    fvec4 c = *(const fvec4*)(src + 4);
    uvec4 o;
    o.x = (unsigned)f2bf(a.x) | ((unsigned)f2bf(a.y) << 16);
    o.y = (unsigned)f2bf(a.z) | ((unsigned)f2bf(a.w) << 16);
    o.z = (unsigned)f2bf(c.x) | ((unsigned)f2bf(c.y) << 16);
    o.w = (unsigned)f2bf(c.z) | ((unsigned)f2bf(c.w) << 16);
    *(uvec4*)(xb + e) = o;
}

// ---------------- one recurrence step: fused 3xGEMM + gate ----------------
// R1 post-mortem: step loop is LDS-pipe-bound (DS ~2240 cyc/CU/k-iter vs MFMA 931).
// Fix: B operands (weights) load global->VGPR directly in MFMA fragment layout
// (lane's 16B slice W[cg][k0+ks*32+(lane>>4)*8] is contiguous), software-pipelined
// one k-iter ahead. Removes 24KB LDS writes + 48KB LDS reads per CU per k-iter.
// LDS now stages only the A (activation) tile: double-buffered, one barrier/k-iter.
__global__ __launch_bounds__(256, 2) void step_kernel(
    const unsigned short* __restrict__ xb,     // bf16 [TSEQ][BATCH][DIN]
    const unsigned short* __restrict__ Wb,     // bf16 [3][HID][CIN]
    const float* __restrict__ bfv,
    const float* __restrict__ bgv,
    const float* __restrict__ bhv,
    const unsigned short* __restrict__ hin,    // bf16 [BATCH][HID]
    unsigned short* __restrict__ hout,         // bf16 [BATCH][HID]
    int t)
{
    __shared__ __align__(16) char lds[2][A_BYTES];   // 34816 B

    const int tid  = threadIdx.x;
    const int bid  = blockIdx.x;
    // n-affinity XCD swizzle: XCD (bid&7) sees n_tiles {4k..4k+3} -> 1.18 MB weight slice in L2
    const int n_tile = ((bid & 7) << 2) | ((bid >> 3) & 3);   // 0..31
    const int m_tile = bid >> 5;                              // 0..15
    const int m0 = m_tile * BM;
    const int n0 = n_tile * BN;

    const int lane = tid & 63;
    const int wave = tid >> 6;       // 0..3
    const int wm = wave >> 1;        // 0..1 : 64-row half
    const int wn = wave & 1;         // 0..1 : 16-col half

    // DMA lane mapping inside an 8-row x 128 B chunk
    const int drow = lane >> 3;          // 0..7
    const int dcol = (lane & 7) * 8;     // elem col 0..56

    f32x4 acc[3][4] = {};

    const int cg = n0 + wn * 16 + (lane & 15);
    const float biasF = bfv[cg];
    const float biasG = bgv[cg];
    const float biasH = bhv[cg];

    const unsigned short* xsrc = xb + (size_t)t * BATCH * DIN;

    // precomputed A-fragment read offsets (bytes)
    int aoff[4];
#pragma unroll
    for (int mt = 0; mt < 4; ++mt) {
        int r = wm * 64 + mt * 16 + (lane & 15);
        aoff[mt] = (r >> 3) * CHUNK + (r & 7) * 128;
    }
    const int kboff = (lane >> 4) * 16;   // this lane's 8-elem K-slice within a 128-B row

    // per-lane B base pointers (fragment layout: col cg, k-slot (lane>>4)*8)
    const unsigned short* wbase[3];
#pragma unroll
    for (int mat = 0; mat < 3; ++mat)
        wbase[mat] = Wb + (size_t)mat * (HID * CIN) + (size_t)cg * CIN + ((lane >> 4) * 8);

    // B register double-buffer: bq = current k-iter, loaded one iter ahead
    bf16x8 bq[3][2];
#pragma unroll
    for (int mat = 0; mat < 3; ++mat)
#pragma unroll
        for (int ks = 0; ks < 2; ++ks)
            bq[mat][ks] = *(const bf16x8*)(wbase[mat] + ks * 32);

    auto stage = [&](int ki, int bb) {
        char* base = lds[bb];
        const int k0 = ki * BK;
        const unsigned short* asrc;
        int astride;
        if (k0 < DIN) { asrc = xsrc + k0;        astride = DIN; }
        else          { asrc = hin + (k0 - DIN); astride = HID; }
        // A: wave w stages chunks 4w..4w+3 (rows 32w..32w+31)
#pragma unroll
        for (int c = 0; c < 4; ++c) {
            int chunk = wave * 4 + c;
            gload_lds16(asrc + (size_t)(m0 + chunk * 8 + drow) * astride + dcol,
                        base + chunk * CHUNK);
        }
    };

    stage(0, 0);
    for (int ki = 0; ki < KITERS; ++ki) {
        const int bb = ki & 1;
        __syncthreads();                              // drains DMA(ki); prior readers done
        bf16x8 bqn[3][2];
        if (ki < KITERS - 1) {
            // issue next-iter B loads FIRST (oldest in vmcnt order), then A DMA;
            // both complete under this iter's ~900-cyc compute phase
            const int k0n = (ki + 1) * BK;
#pragma unroll
            for (int mat = 0; mat < 3; ++mat)
#pragma unroll
                for (int ks = 0; ks < 2; ++ks)
                    bqn[mat][ks] = *(const bf16x8*)(wbase[mat] + k0n + ks * 32);
            stage(ki + 1, bb ^ 1);
        }
        const char* base = lds[bb];
#pragma unroll
        for (int ks = 0; ks < 2; ++ks) {
            const int kb = ks * 64 + kboff;
            bf16x8 af[4];
#pragma unroll
            for (int mt = 0; mt < 4; ++mt)
                af[mt] = *(const bf16x8*)(base + aoff[mt] + kb);
#pragma unroll
            for (int mat = 0; mat < 3; ++mat)
#pragma unroll
                for (int mt = 0; mt < 4; ++mt)
                    acc[mat][mt] = __builtin_amdgcn_mfma_f32_16x16x32_bf16(
                        af[mt], bq[mat][ks], acc[mat][mt], 0, 0, 0);
        }
        if (ki < KITERS - 1) {
#pragma unroll
            for (int mat = 0; mat < 3; ++mat)
#pragma unroll
                for (int ks = 0; ks < 2; ++ks)
                    bq[mat][ks] = bqn[mat][ks];
        }
    }

    // epilogue: gate + NT store bf16 h_out
    // C/D layout (16x16x32): col = lane&15, row = (lane>>4)*4 + reg   [m89-verified]
#pragma unroll
    for (int mt = 0; mt < 4; ++mt) {
        int rbase = m0 + wm * 64 + mt * 16 + (lane >> 4) * 4;
#pragma unroll
        for (int r = 0; r < 4; ++r) {
            float f  = acc[0][mt][r] + biasF;
            float g  = acc[1][mt][r] + biasG;
            float hh = acc[2][mt][r] + biasH;
            float gate = 1.0f / (1.0f + __expf(f));   // sigmoid(-f)
            float nh = hh + gate * (g - hh);
            __builtin_nontemporal_store(f2bf(nh),
                hout + (size_t)(rbase + r) * HID + cg);
        }
    }
}

// ---------------- final FC: out[2048][2] = h @ Wfc^T + bfc ----------------
__global__ __launch_bounds__(256) void fc_kernel(const unsigned short* __restrict__ h,
                                                 const float* __restrict__ Wfc,
                                                 const float* __restrict__ bfc,
                                                 float* __restrict__ out) {
    int row = blockIdx.x;
    int tid = threadIdx.x;
    const unsigned short* hr = h + (size_t)row * HID;
    ushort4 hv = *(const ushort4*)(hr + tid * 4);
    float h0 = bf2f(hv.x), h1 = bf2f(hv.y), h2 = bf2f(hv.z), h3 = bf2f(hv.w);
    float4 w0 = *(const float4*)(Wfc + tid * 4);
    float4 w1 = *(const float4*)(Wfc + HID + tid * 4);
    float a0 = h0 * w0.x + h1 * w0.y + h2 * w0.z + h3 * w0.w;
    float a1 = h0 * w1.x + h1 * w1.y + h2 * w1.z + h3 * w1.w;
#pragma unroll
    for (int off = 32; off > 0; off >>= 1) {
        a0 += __shfl_down(a0, off);
        a1 += __shfl_down(a1, off);
    }
    __shared__ float red[2][4];
    if ((tid & 63) == 0) { red[0][tid >> 6] = a0; red[1][tid >> 6] = a1; }
    __syncthreads();
    if (tid == 0) out[(size_t)row * 2 + 0] = red[0][0] + red[0][1] + red[0][2] + red[0][3] + bfc[0];
    if (tid == 1) out[(size_t)row * 2 + 1] = red[1][0] + red[1][1] + red[1][2] + red[1][3] + bfc[1];
}

extern "C" void kernel_launch(void* const* d_in, const int* in_sizes, int n_in,
                              void* d_out, int out_size, void* d_ws, size_t ws_size,
                              hipStream_t stream) {
    const float* x   = (const float*)d_in[0];
    const float* Wf  = (const float*)d_in[1];
    const float* bfv = (const float*)d_in[2];
    const float* Wg  = (const float*)d_in[3];
    const float* bgv = (const float*)d_in[4];
    const float* Wh  = (const float*)d_in[5];
    const float* bhv = (const float*)d_in[6];
    const float* Wfc = (const float*)d_in[7];
    const float* bfc = (const float*)d_in[8];
    float* out = (float*)d_out;

    char* ws = (char*)d_ws;
    unsigned short* Wb = (unsigned short*)ws;                       // 9.4 MB
    size_t wb_bytes = (size_t)3 * HID * CIN * 2;
    size_t h_bytes  = (size_t)BATCH * HID * 2;                      // 4 MB
    unsigned short* h0 = (unsigned short*)(ws + wb_bytes);
    unsigned short* h1 = (unsigned short*)(ws + wb_bytes + h_bytes);
    unsigned short* xbuf = (unsigned short*)(ws + wb_bytes + 2 * h_bytes);  // 128 MB
    // total ws use ~146 MB (harness ws ~1 GiB)

    convert_w<<<dim3(768, 3), 256, 0, stream>>>(Wf, Wg, Wh, Wb);
    convert_x<<<32768, 256, 0, stream>>>(x, xbuf);
    (void)hipMemsetAsync(h0, 0, h_bytes, stream);                   // h_0 = 0 (capturable)

    unsigned short* bufs[2] = {h0, h1};
    for (int t = 0; t < TSEQ; ++t) {
        step_kernel<<<512, 256, 0, stream>>>(xbuf, Wb, bfv, bgv, bhv,
                                             bufs[t & 1], bufs[(t + 1) & 1], t);
    }
    // after 64 steps, final h is in bufs[0]
    fc_kernel<<<BATCH, 256, 0, stream>>>(h0, Wfc, bfc, out);
}

// Round 3
// 1874.219 us; speedup vs baseline: 2.1958x; 1.6329x over previous
//
#include <hip/hip_runtime.h>
#include <stdint.h>

#define BATCH 2048
#define TSEQ  64
#define DIN   512
#define HID   1024
#define CIN   1536   // DIN + HID

#define BM 128
#define BN 32
#define BK 64
#define KITERS (CIN / BK)   // 24

// LDS geometry: 8-row chunks of 128 B rows (1024 B data) + 64 B pad -> stride 1088 B.
// (r>>3) chunk step lands +16 banks; row-within-chunk +0; lane quads +4; 8/8 lane split
// covers +0/+16 -> b128 fragment reads hit all 32 banks exactly 8x (optimal throughput).
#define CHUNK   1088
#define A_CHUNKS 16                     // 128 rows
#define B_CHUNKS 4                      // 32 rows per matrix
#define A_BYTES (A_CHUNKS * CHUNK)      // 17408
#define B_MAT   (B_CHUNKS * CHUNK)      // 4352
#define B_BYTES (3 * B_MAT)             // 13056
// A triple-buffered (2-phase prefetch lead) + B double-buffered (1-phase lead):
// 3*17408 + 2*13056 = 78336 B/block; x2 blocks = 156672 <= 163840 -> still 2 blocks/CU.

typedef __attribute__((ext_vector_type(8))) short bf16x8;
typedef __attribute__((ext_vector_type(4))) float f32x4;
typedef __attribute__((ext_vector_type(4))) float fvec4;
typedef __attribute__((ext_vector_type(4))) unsigned int uvec4;

// RNE float -> bf16 (bits)
__device__ __forceinline__ unsigned short f2bf(float f) {
    unsigned int u = __float_as_uint(f);
    u += 0x7fffu + ((u >> 16) & 1u);
    return (unsigned short)(u >> 16);
}
__device__ __forceinline__ float bf2f(unsigned short u) {
    return __uint_as_float(((unsigned int)u) << 16);
}

// async global->LDS, 16B per lane; lane i lands at ldsbase + i*16 (wave-uniform base).
__device__ __forceinline__ void gload_lds16(const void* g, void* lds) {
    __builtin_amdgcn_global_load_lds(
        (const __attribute__((address_space(1))) void*)(uintptr_t)g,
        (__attribute__((address_space(3))) void*)(unsigned)(uintptr_t)lds,
        16, 0, 0);
}

// ---------------- weight conversion: fp32 -> bf16, 3 matrices [HID][CIN] ----------------
__global__ __launch_bounds__(256) void convert_w(const float* __restrict__ Wf,
                                                 const float* __restrict__ Wg,
                                                 const float* __restrict__ Wh,
                                                 unsigned short* __restrict__ Wb) {
    int mat = blockIdx.y;
    const float* src = (mat == 0) ? Wf : ((mat == 1) ? Wg : Wh);
    size_t base = (size_t)mat * (size_t)(HID * CIN);
    size_t idx = ((size_t)blockIdx.x * 256 + threadIdx.x) * 8;
    const fvec4* s = (const fvec4*)(src + idx);
    fvec4 a = s[0], b = s[1];
    uvec4 o;
    o.x = (unsigned)f2bf(a.x) | ((unsigned)f2bf(a.y) << 16);
    o.y = (unsigned)f2bf(a.z) | ((unsigned)f2bf(a.w) << 16);
    o.z = (unsigned)f2bf(b.x) | ((unsigned)f2bf(b.y) << 16);
    o.w = (unsigned)f2bf(b.z) | ((unsigned)f2bf(b.w) << 16);
    *(uvec4*)(Wb + base + idx) = o;
}

// ---------------- x conversion: [B][T][D] fp32 -> [T][B][D] bf16 (time-major) ----------------
__global__ __launch_bounds__(256) void convert_x(const float* __restrict__ x,
                                                 unsigned short* __restrict__ xb) {
    size_t e = ((size_t)blockIdx.x * 256 + threadIdx.x) * 8;
    int t   = (int)(e / ((size_t)BATCH * DIN));
    int rem = (int)(e % ((size_t)BATCH * DIN));
    int b = rem / DIN;
    int d = rem % DIN;
    const float* src = x + ((size_t)b * TSEQ + t) * DIN + d;
    fvec4 a = *(const fvec4*)src;
    fvec4 c = *(const fvec4*)(src + 4);
    uvec4 o;
    o.x = (unsigned)f2bf(a.x) | ((unsigned)f2bf(a.y) << 16);
    o.y = (unsigned)f2bf(a.z) | ((unsigned)f2bf(a.w) << 16);
    o.z = (unsigned)f2bf(c.x) | ((unsigned)f2bf(c.y) << 16);
    o.w = (unsigned)f2bf(c.z) | ((unsigned)f2bf(c.w) << 16);
    *(uvec4*)(xb + e) = o;
}

// ---------------- one recurrence step: fused 3xGEMM + gate ----------------
// R3: counted-vmcnt pipeline (T4). Per-wave issue sequence: ...B(p), A(p+1), B(p+1), A(p+2)...
// (7 loads/wave/phase: 4 A-chunks + 3 B-units, uniform across waves). Top of phase p:
//   s_waitcnt lgkmcnt(0)        -> my reads of phase p-1's buffers complete (overwrite-safe)
//   s_waitcnt vmcnt(4)          -> retires oldest 7 = {A(p), B(p)}: MY tile-p staging landed
//   s_barrier                   -> hence ALL waves' tile-p staging landed; no drain-to-0
// A(p+2)/B(p+1) stay in flight ACROSS the barrier with a full ~2000-cyc phase of cover
// (>= worst-case HBM latency ~900cy), so the pre-barrier waits are ~free.
__global__ __launch_bounds__(256, 2) void step_kernel(
    const unsigned short* __restrict__ xb,     // bf16 [TSEQ][BATCH][DIN]
    const unsigned short* __restrict__ Wb,     // bf16 [3][HID][CIN]
    const float* __restrict__ bfv,
    const float* __restrict__ bgv,
    const float* __restrict__ bhv,
    const unsigned short* __restrict__ hin,    // bf16 [BATCH][HID]
    unsigned short* __restrict__ hout,         // bf16 [BATCH][HID]
    int t)
{
    __shared__ __align__(16) char ldsA[3][A_BYTES];   // 52224 B
    __shared__ __align__(16) char ldsB[2][B_BYTES];   // 26112 B

    const int tid  = threadIdx.x;
    const int bid  = blockIdx.x;
    // n-affinity XCD swizzle: XCD (bid&7) sees n_tiles {4k..4k+3} -> 1.18 MB weight slice in L2
    const int n_tile = ((bid & 7) << 2) | ((bid >> 3) & 3);   // 0..31
    const int m_tile = bid >> 5;                              // 0..15
    const int m0 = m_tile * BM;
    const int n0 = n_tile * BN;

    const int lane = tid & 63;
    const int wave = tid >> 6;       // 0..3
    const int wm = wave >> 1;        // 0..1 : 64-row half
    const int wn = wave & 1;         // 0..1 : 16-col half

    // DMA lane mapping inside an 8-row x 128 B chunk
    const int drow = lane >> 3;          // 0..7
    const int dcol = (lane & 7) * 8;     // elem col 0..56

    f32x4 acc[3][4] = {};

    const int cg = n0 + wn * 16 + (lane & 15);
    const float biasF = bfv[cg];
    const float biasG = bgv[cg];
    const float biasH = bhv[cg];

    const unsigned short* xsrc = xb + (size_t)t * BATCH * DIN;

    // precomputed A-fragment read offsets (bytes)
    int aoff[4];
#pragma unroll
    for (int mt = 0; mt < 4; ++mt) {
        int r = wm * 64 + mt * 16 + (lane & 15);
        aoff[mt] = (r >> 3) * CHUNK + (r & 7) * 128;
    }
    const int nloc = wn * 16 + (lane & 15);
    const int boff = (nloc >> 3) * CHUNK + (nloc & 7) * 128;
    const int kboff = (lane >> 4) * 16;   // this lane's 8-elem K-slice within a 128-B row

    auto stageA = [&](int ki, char* base) {
        const int k0 = ki * BK;
        const unsigned short* asrc;
        int astride;
        if (k0 < DIN) { asrc = xsrc + k0;        astride = DIN; }
        else          { asrc = hin + (k0 - DIN); astride = HID; }
        // wave w stages chunks 4w..4w+3 (rows 32w..32w+31): 4 loads/wave
#pragma unroll
        for (int c = 0; c < 4; ++c) {
            int chunk = wave * 4 + c;
            gload_lds16(asrc + (size_t)(m0 + chunk * 8 + drow) * astride + dcol,
                        base + chunk * CHUNK);
        }
    };
    auto stageB = [&](int ki, char* base) {
        const int k0 = ki * BK;
        // 12 chunk-units (mat = u>>2, chunk = u&3); wave w stages u = 3w..3w+2: 3 loads/wave
#pragma unroll
        for (int j = 0; j < 3; ++j) {
            int u = wave * 3 + j;
            int mat = u >> 2, chunk = u & 3;
            gload_lds16(Wb + (size_t)mat * (HID * CIN) + (size_t)(n0 + chunk * 8 + drow) * CIN
                           + k0 + dcol,
                        base + mat * B_MAT + chunk * CHUNK);
        }
    };
    auto compute = [&](const char* baseA, const char* baseB) {
#pragma unroll
        for (int ks = 0; ks < 2; ++ks) {
            const int kb = ks * 64 + kboff;
            bf16x8 af[4];
#pragma unroll
            for (int mt = 0; mt < 4; ++mt)
                af[mt] = *(const bf16x8*)(baseA + aoff[mt] + kb);
#pragma unroll
            for (int mat = 0; mat < 3; ++mat) {
                bf16x8 bq = *(const bf16x8*)(baseB + mat * B_MAT + boff + kb);
#pragma unroll
                for (int mt = 0; mt < 4; ++mt)
                    acc[mat][mt] = __builtin_amdgcn_mfma_f32_16x16x32_bf16(
                        af[mt], bq, acc[mat][mt], 0, 0, 0);
            }
        }
    };

    // prologue issue order (must match steady-state vmcnt accounting): A(0), B(0), A(1)
    stageA(0, ldsA[0]);
    stageB(0, ldsB[0]);
    stageA(1, ldsA[1]);

#pragma unroll
    for (int p = 0; p < KITERS - 1; ++p) {            // phases 0..22
        // single asm block: waits + barrier, fully ordered vs all memory ops
        asm volatile("s_waitcnt vmcnt(4) lgkmcnt(0)\n\ts_barrier" ::: "memory");
        stageB(p + 1, ldsB[(p + 1) & 1]);             // 1-phase lead (L2-resident weights)
        if (p + 2 < KITERS) stageA(p + 2, ldsA[(p + 2) % 3]);  // 2-phase lead (x/h via L3/HBM)
        compute(ldsA[p % 3], ldsB[p & 1]);
    }
    // peeled last phase (p = 23): nothing left in flight to keep -> full drain
    asm volatile("s_waitcnt vmcnt(0) lgkmcnt(0)\n\ts_barrier" ::: "memory");
    compute(ldsA[(KITERS - 1) % 3], ldsB[(KITERS - 1) & 1]);

    // epilogue: gate + NT store bf16 h_out
    // C/D layout (16x16x32): col = lane&15, row = (lane>>4)*4 + reg   [m89-verified]
#pragma unroll
    for (int mt = 0; mt < 4; ++mt) {
        int rbase = m0 + wm * 64 + mt * 16 + (lane >> 4) * 4;
#pragma unroll
        for (int r = 0; r < 4; ++r) {
            float f  = acc[0][mt][r] + biasF;
            float g  = acc[1][mt][r] + biasG;
            float hh = acc[2][mt][r] + biasH;
            float gate = 1.0f / (1.0f + __expf(f));   // sigmoid(-f)
            float nh = hh + gate * (g - hh);
            __builtin_nontemporal_store(f2bf(nh),
                hout + (size_t)(rbase + r) * HID + cg);
        }
    }
}

// ---------------- final FC: out[2048][2] = h @ Wfc^T + bfc ----------------
__global__ __launch_bounds__(256) void fc_kernel(const unsigned short* __restrict__ h,
                                                 const float* __restrict__ Wfc,
                                                 const float* __restrict__ bfc,
                                                 float* __restrict__ out) {
    int row = blockIdx.x;
    int tid = threadIdx.x;
    const unsigned short* hr = h + (size_t)row * HID;
    ushort4 hv = *(const ushort4*)(hr + tid * 4);
    float h0 = bf2f(hv.x), h1 = bf2f(hv.y), h2 = bf2f(hv.z), h3 = bf2f(hv.w);
    float4 w0 = *(const float4*)(Wfc + tid * 4);
    float4 w1 = *(const float4*)(Wfc + HID + tid * 4);
    float a0 = h0 * w0.x + h1 * w0.y + h2 * w0.z + h3 * w0.w;
    float a1 = h0 * w1.x + h1 * w1.y + h2 * w1.z + h3 * w1.w;
#pragma unroll
    for (int off = 32; off > 0; off >>= 1) {
        a0 += __shfl_down(a0, off);
        a1 += __shfl_down(a1, off);
    }
    __shared__ float red[2][4];
    if ((tid & 63) == 0) { red[0][tid >> 6] = a0; red[1][tid >> 6] = a1; }
    __syncthreads();
    if (tid == 0) out[(size_t)row * 2 + 0] = red[0][0] + red[0][1] + red[0][2] + red[0][3] + bfc[0];
    if (tid == 1) out[(size_t)row * 2 + 1] = red[1][0] + red[1][1] + red[1][2] + red[1][3] + bfc[1];
}

extern "C" void kernel_launch(void* const* d_in, const int* in_sizes, int n_in,
                              void* d_out, int out_size, void* d_ws, size_t ws_size,
                              hipStream_t stream) {
    const float* x   = (const float*)d_in[0];
    const float* Wf  = (const float*)d_in[1];
    const float* bfv = (const float*)d_in[2];
    const float* Wg  = (const float*)d_in[3];
    const float* bgv = (const float*)d_in[4];
    const float* Wh  = (const float*)d_in[5];
    const float* bhv = (const float*)d_in[6];
    const float* Wfc = (const float*)d_in[7];
    const float* bfc = (const float*)d_in[8];
    float* out = (float*)d_out;

    char* ws = (char*)d_ws;
    unsigned short* Wb = (unsigned short*)ws;                       // 9.4 MB
    size_t wb_bytes = (size_t)3 * HID * CIN * 2;
    size_t h_bytes  = (size_t)BATCH * HID * 2;                      // 4 MB
    unsigned short* h0 = (unsigned short*)(ws + wb_bytes);
    unsigned short* h1 = (unsigned short*)(ws + wb_bytes + h_bytes);
    unsigned short* xbuf = (unsigned short*)(ws + wb_bytes + 2 * h_bytes);  // 128 MB
    // total ws use ~146 MB (harness ws ~1 GiB)

    convert_w<<<dim3(768, 3), 256, 0, stream>>>(Wf, Wg, Wh, Wb);
    convert_x<<<32768, 256, 0, stream>>>(x, xbuf);
    (void)hipMemsetAsync(h0, 0, h_bytes, stream);                   // h_0 = 0 (capturable)

    unsigned short* bufs[2] = {h0, h1};
    for (int t = 0; t < TSEQ; ++t) {
        step_kernel<<<512, 256, 0, stream>>>(xbuf, Wb, bfv, bgv, bhv,
                                             bufs[t & 1], bufs[(t + 1) & 1], t);
    }
    // after 64 steps, final h is in bufs[0]
    fc_kernel<<<BATCH, 256, 0, stream>>>(h0, Wfc, bfc, out);
}